// Round 12
// baseline (157.907 us; speedup 1.0000x reference)
//
#include <hip/hip_runtime.h>
#include <math.h>

#define T_TOK 8192
#define HID   2880
#define NE    128
#define TOPK  4
#define NKS   (HID / 32)     // 90 K-steps of 32
#define TM    64             // tokens per tile
#define NTILE (T_TOK / TM)   // 128 tiles
#define SPLITK 4
#define LROW  40             // LDS row stride in halves (80 B)
#define LPLANE (TM * LROW)   // one h- or l-plane, in halves (2560)

typedef _Float16 f16x8 __attribute__((ext_vector_type(8)));
typedef _Float16 f16x4 __attribute__((ext_vector_type(4)));
typedef float    f32x4 __attribute__((ext_vector_type(4)));

// ---------------------------------------------------------------------------
// Kernel 0: W (fp32) -> fragment-linear fp16 hi/lo planes, scaled x32 (keeps
// lo out of denormals; 2^-5 folded into the epilogue). Fragment (32-k step
// gs, expert-group j, plane p) at ((gs*8+j)*2+p)*512 halves; lane
// l=(oct<<4)|(n&15) holds 8 k-consecutive halves = mfma_16x16x32 B chunk.
// Block 0 also zeroes the per-tile arrival counters (stream-ordered before
// the fused gemm -> deterministic across graph replays).
// ---------------------------------------------------------------------------
__global__ __launch_bounds__(256) void convert_w(const float* __restrict__ w,
                                                 _Float16* __restrict__ wc,
                                                 int* __restrict__ ctr) {
  if (blockIdx.x == 0 && threadIdx.x < NTILE) ctr[threadIdx.x] = 0;
  const int c = blockIdx.x * 256 + threadIdx.x;   // one 8-k chunk of one expert
  if (c >= NE * (HID / 8)) return;
  const int n  = c / (HID / 8);
  const int k8 = c % (HID / 8);
  const float4 v0 = *(const float4*)(w + (size_t)n * HID + k8 * 8);
  const float4 v1 = *(const float4*)(w + (size_t)n * HID + k8 * 8 + 4);
  const float f[8] = {v0.x, v0.y, v0.z, v0.w, v1.x, v1.y, v1.z, v1.w};
  f16x8 h, l;
#pragma unroll
  for (int i = 0; i < 8; ++i) {
    const float s = f[i] * 32.0f;
    const _Float16 hi = (_Float16)s;
    h[i] = hi;
    l[i] = (_Float16)(s - (float)hi);
  }
  const int gs   = k8 >> 2;
  const int oct  = k8 & 3;
  const int j    = n >> 4;
  const int lane = (oct << 4) | (n & 15);
  _Float16* base = wc + ((size_t)(gs * 8 + j) * 2) * 512 + lane * 8;
  *(f16x8*)(base)       = h;
  *(f16x8*)(base + 512) = l;
}

// ---------------------------------------------------------------------------
// Kernel 1: FUSED gemm + last-arriver topk.
// GEMM body = R8 best-known: fp16x2 MFMA emulation (xh*wh + xl*wh + xh*wl,
// *2^-5), 64 tok x 128 exp tile, 4 waves, split-K=4, double-buffered LDS,
// x 2 steps ahead, B 1 step ahead, s=bid&3 swizzle (XCD streams one wc chunk).
// Epilogue: write plane -> threadfence -> atomicAdd(ctr[tile]) (512 total,
// uncontended); the 4th arriver reduces the 4 cache-hot planes + bias, does
// per-token top-4 (desc, lower-index tie-break = jax.lax.top_k) + softmax,
// writes scores/indices, and a per-tile LDS histogram -> tileHist (no global
// atomic storms — R5 lesson).
// ---------------------------------------------------------------------------
struct BF { f16x8 h[2], l[2]; };

__device__ __forceinline__ void load_b(const _Float16* __restrict__ wc, int wn,
                                       int lane, int gs, BF& f) {
#pragma unroll
  for (int g = 0; g < 2; ++g) {
    const _Float16* bp = wc + ((size_t)(gs * 8 + wn * 2 + g) * 2) * 512 + lane * 8;
    f.h[g] = *(const f16x8*)bp;
    f.l[g] = *(const f16x8*)(bp + 512);
  }
}

__device__ __forceinline__ void load_x(const float* __restrict__ x, int m0,
                                       int t, int gs, float4 (&xr)[2]) {
#pragma unroll
  for (int j = 0; j < 2; ++j) {
    const int c   = j * 256 + t;
    const int row = c >> 3;
    const int kq  = c & 7;
    xr[j] = *(const float4*)(x + (size_t)(m0 + row) * HID + gs * 32 + kq * 4);
  }
}

__device__ __forceinline__ void stage_x(const float4 (&xr)[2],
                                        _Float16* __restrict__ buf, int t) {
#pragma unroll
  for (int j = 0; j < 2; ++j) {
    const int c   = j * 256 + t;
    const int row = c >> 3;
    const int kq  = c & 7;
    const float a[4] = {xr[j].x, xr[j].y, xr[j].z, xr[j].w};
    f16x4 h, l;
#pragma unroll
    for (int i = 0; i < 4; ++i) {
      const _Float16 hi = (_Float16)a[i];
      h[i] = hi;
      l[i] = (_Float16)(a[i] - (float)hi);
    }
    const int off = row * LROW + kq * 4;
    *(f16x4*)&buf[off]          = h;
    *(f16x4*)&buf[LPLANE + off] = l;
  }
}

__device__ __forceinline__ void mfma_step(const _Float16* __restrict__ buf,
                                          const BF& f, int lane,
                                          f32x4 (&acc)[4][2]) {
#pragma unroll
  for (int mi = 0; mi < 4; ++mi) {
    const int off = (mi * 16 + (lane & 15)) * LROW + (lane >> 4) * 8;
    const f16x8 ah = *(const f16x8*)&buf[off];
    const f16x8 al = *(const f16x8*)&buf[LPLANE + off];
#pragma unroll
    for (int g = 0; g < 2; ++g) {
      acc[mi][g] = __builtin_amdgcn_mfma_f32_16x16x32_f16(ah, f.h[g], acc[mi][g], 0, 0, 0);
      acc[mi][g] = __builtin_amdgcn_mfma_f32_16x16x32_f16(al, f.h[g], acc[mi][g], 0, 0, 0);
      acc[mi][g] = __builtin_amdgcn_mfma_f32_16x16x32_f16(ah, f.l[g], acc[mi][g], 0, 0, 0);
    }
  }
}

__global__ __launch_bounds__(256, 2) void gemm_topk(const float* __restrict__ x,
                                                    const _Float16* __restrict__ wc,
                                                    const float* __restrict__ bias,
                                                    float* __restrict__ part,
                                                    int* __restrict__ ctr,
                                                    float* __restrict__ tileHist,
                                                    float* __restrict__ out) {
  __shared__ _Float16 xsh[2 * 2 * LPLANE];   // 20480 B
  __shared__ int hist[NE];
  __shared__ int lastFlag;

  const int bid = blockIdx.x;
  const int s    = bid & 3;                              // K-chunk, fixed per XCD
  const int tile = ((bid >> 3) << 1) | ((bid & 7) >> 2); // token tile
  const int m0   = tile * TM;

  const int t    = threadIdx.x;
  const int lane = t & 63;
  const int wn   = t >> 6;       // expert quarter / wave id

  const int kbase = NKS / SPLITK, krem = NKS % SPLITK;
  const int cnt   = kbase + (s < krem ? 1 : 0);
  const int st0   = s * kbase + (s < krem ? s : krem);

  _Float16* buf0 = xsh;
  _Float16* buf1 = xsh + 2 * LPLANE;

  f32x4 acc[4][2] = {};
  float4 xrA[2], xrB[2];
  BF bA, bB;

  load_x(x, m0, t, st0, xrA);
  load_b(wc, wn, lane, st0, bA);
  stage_x(xrA, buf0, t);
  if (cnt > 1) load_x(x, m0, t, st0 + 1, xrB);
  __syncthreads();

  int st = 0;
  for (;;) {
    if (st + 1 < cnt) load_b(wc, wn, lane, st0 + st + 1, bB);
    if (st + 2 < cnt) load_x(x, m0, t, st0 + st + 2, xrA);
    mfma_step(buf0, bA, lane, acc);
    if (st + 1 < cnt) stage_x(xrB, buf1, t);
    __syncthreads();
    if (st + 1 >= cnt) break;

    if (st + 2 < cnt) load_b(wc, wn, lane, st0 + st + 2, bA);
    if (st + 3 < cnt) load_x(x, m0, t, st0 + st + 3, xrB);
    mfma_step(buf1, bB, lane, acc);
    if (st + 2 < cnt) stage_x(xrA, buf0, t);
    __syncthreads();
    st += 2;
    if (st >= cnt) break;
  }

  // write this K-chunk's plane (C/D: col=lane&15 expert, row=(lane>>4)*4+reg)
  float* pl = part + (size_t)s * T_TOK * NE;
  const int e0 = wn * 32 + (lane & 15);
  const int r0 = m0 + (lane >> 4) * 4;
#pragma unroll
  for (int mi = 0; mi < 4; ++mi)
#pragma unroll
    for (int g = 0; g < 2; ++g) {
      float* pp = pl + (size_t)(r0 + mi * 16) * NE + e0 + g * 16;
#pragma unroll
      for (int r = 0; r < 4; ++r) pp[(size_t)r * NE] = acc[mi][g][r] * 0.03125f;
    }

  // ---- arrival protocol: 4th block of this tile does the reduce+topk ----
  __threadfence();                       // release plane writes (device scope)
  __syncthreads();                       // all plane stores issued+fenced
  if (t == 0) lastFlag = (atomicAdd(&ctr[tile], 1) == SPLITK - 1);
  __syncthreads();
  if (!lastFlag) return;
  __threadfence();                       // acquire: other planes now visible

  for (int e = t; e < NE; e += 256) hist[e] = 0;
  __syncthreads();

  // each wave handles 16 tokens; planes are L2/IC-hot
  for (int i = 0; i < 16; ++i) {
    const int tok = m0 + wn * 16 + i;
    float v0 = 0.f, v1 = 0.f;
#pragma unroll
    for (int sp = 0; sp < SPLITK; ++sp) {   // fixed order -> deterministic
      const float2 p = ((const float2*)(part + ((size_t)sp * T_TOK + tok) * NE))[lane];
      v0 += p.x;
      v1 += p.y;
    }
    const float2 b2 = ((const float2*)bias)[lane];
    v0 += b2.x;
    v1 += b2.y;
    const int i0 = 2 * lane, i1 = 2 * lane + 1;

    float topv[TOPK];
    int   topi[TOPK];
#pragma unroll
    for (int r = 0; r < TOPK; ++r) {
      float bv; int bi;
      if (v0 >= v1) { bv = v0; bi = i0; }   // i0 < i1 implements the tie-break
      else          { bv = v1; bi = i1; }
#pragma unroll
      for (int off = 32; off > 0; off >>= 1) {
        const float ov = __shfl_xor(bv, off);
        const int   oi = __shfl_xor(bi, off);
        if (ov > bv || (ov == bv && oi < bi)) { bv = ov; bi = oi; }
      }
      topv[r] = bv; topi[r] = bi;
      if (bi == i0) v0 = -INFINITY;
      if (bi == i1) v1 = -INFINITY;
    }

    const float m = topv[0];
    float sum = 0.f;
#pragma unroll
    for (int r = 0; r < TOPK; ++r) sum += expf(topv[r] - m);

    if (lane < TOPK) {
      out[(size_t)tok * TOPK + lane] = expf(topv[lane] - m) / sum;
      out[(size_t)T_TOK * TOPK + (size_t)tok * TOPK + lane] = (float)topi[lane];
      atomicAdd(&hist[topi[lane]], 1);   // LDS atomic, cheap
    }
  }
  __syncthreads();
  for (int e = t; e < NE; e += 256)
    tileHist[(size_t)tile * NE + e] = (float)hist[e];
}

// ---------------------------------------------------------------------------
// Kernel 2: fold 128 per-tile histograms (64 KB) into counts. One block.
// ---------------------------------------------------------------------------
__global__ __launch_bounds__(128) void count_reduce(const float* __restrict__ tileHist,
                                                    float* __restrict__ counts) {
  const int e = threadIdx.x;
  float c = 0.f;
  for (int tl = 0; tl < NTILE; ++tl) c += tileHist[(size_t)tl * NE + e];
  counts[e] = c;
}

extern "C" void kernel_launch(void* const* d_in, const int* in_sizes, int n_in,
                              void* d_out, int out_size, void* d_ws, size_t ws_size,
                              hipStream_t stream) {
  const float* x    = (const float*)d_in[0];
  const float* w    = (const float*)d_in[1];
  const float* bias = (const float*)d_in[2];
  float* out = (float*)d_out;

  char* ws = (char*)d_ws;
  float*    part     = (float*)ws;                                   // 16 MB
  size_t    off      = (size_t)SPLITK * T_TOK * NE * sizeof(float);
  _Float16* wc       = (_Float16*)(ws + off);                        // 1.44 MB
  off += (size_t)NE * HID * 2 * sizeof(_Float16);
  int*      ctr      = (int*)(ws + off);                             // 512 B
  off += NTILE * sizeof(int);
  float*    tileHist = (float*)(ws + off);                           // 64 KB

  convert_w<<<(NE * (HID / 8) + 255) / 256, 256, 0, stream>>>(w, wc, ctr);
  gemm_topk<<<(T_TOK / TM) * SPLITK, 256, 0, stream>>>(x, wc, bias, part, ctr,
                                                       tileHist, out);
  count_reduce<<<1, 128, 0, stream>>>(tileHist, out + 2 * (size_t)T_TOK * TOPK);
}

// Round 13
// 82.527 us; speedup vs baseline: 1.9134x; 1.9134x over previous
//
#include <hip/hip_runtime.h>
#include <math.h>

#define T_TOK 8192
#define HID   2880
#define NE    128
#define TOPK  4
#define NKS   (HID / 32)     // 90 K-steps of 32
#define TM    32             // tokens per tile (32 -> grid 1024 = 4 blocks/CU)
#define NTILE (T_TOK / TM)   // 256 tiles
#define SPLITK 4
#define LROW  40             // LDS row stride in halves (80 B)
#define LPLANE (TM * LROW)   // one h- or l-plane, in halves (1280)

typedef _Float16 f16x8 __attribute__((ext_vector_type(8)));
typedef _Float16 f16x4 __attribute__((ext_vector_type(4)));
typedef float    f32x4 __attribute__((ext_vector_type(4)));

// ---------------------------------------------------------------------------
// Kernel 0: W (fp32) -> fragment-linear fp16 hi/lo planes, scaled x32 (keeps
// lo out of denormals; 2^-5 folded into the epilogue). Fragment (32-k step
// gs, expert-group j, plane p) at ((gs*8+j)*2+p)*512 halves; lane
// l=(oct<<4)|(n&15) holds 8 k-consecutive halves = mfma_16x16x32 B chunk.
// ---------------------------------------------------------------------------
__global__ __launch_bounds__(256) void convert_w(const float* __restrict__ w,
                                                 _Float16* __restrict__ wc) {
  const int c = blockIdx.x * 256 + threadIdx.x;   // one 8-k chunk of one expert
  if (c >= NE * (HID / 8)) return;
  const int n  = c / (HID / 8);
  const int k8 = c % (HID / 8);
  const float4 v0 = *(const float4*)(w + (size_t)n * HID + k8 * 8);
  const float4 v1 = *(const float4*)(w + (size_t)n * HID + k8 * 8 + 4);
  const float f[8] = {v0.x, v0.y, v0.z, v0.w, v1.x, v1.y, v1.z, v1.w};
  f16x8 h, l;
#pragma unroll
  for (int i = 0; i < 8; ++i) {
    const float s = f[i] * 32.0f;
    const _Float16 hi = (_Float16)s;
    h[i] = hi;
    l[i] = (_Float16)(s - (float)hi);
  }
  const int gs   = k8 >> 2;
  const int oct  = k8 & 3;
  const int j    = n >> 4;
  const int lane = (oct << 4) | (n & 15);
  _Float16* base = wc + ((size_t)(gs * 8 + j) * 2) * 512 + lane * 8;
  *(f16x8*)(base)       = h;
  *(f16x8*)(base + 512) = l;
}

// ---------------------------------------------------------------------------
// Kernel 1: partial logits via fp16x2 MFMA emulation of fp32 (R8 body,
// TM 64->32): acc += xh*wh + xl*wh + xh*wl, *2^-5. Tile 32 tok x 128 exp,
// 4 waves (32tok x 32exp each: mi=2 x nj=2, 12 MFMA/32k-step). split-K=4,
// grid 1024 -> 4 blocks/CU, 16 waves/CU (occupancy x2 vs R8, traffic
// IDENTICAL — the one untested no-cost lever). LDS 10.2 KB double-buffered.
// x 2 steps ahead, B 1 step ahead. s=bid&3: XCD (bid%8) streams ONE wc chunk.
// NO cross-block coherence ops (R5/R12 lessons: atomics/threadfence = tens of us).
// ---------------------------------------------------------------------------
struct BF { f16x8 h[2], l[2]; };

__device__ __forceinline__ void load_b(const _Float16* __restrict__ wc, int wn,
                                       int lane, int gs, BF& f) {
#pragma unroll
  for (int g = 0; g < 2; ++g) {
    const _Float16* bp = wc + ((size_t)(gs * 8 + wn * 2 + g) * 2) * 512 + lane * 8;
    f.h[g] = *(const f16x8*)bp;
    f.l[g] = *(const f16x8*)(bp + 512);
  }
}

__device__ __forceinline__ void load_x(const float* __restrict__ x, int m0,
                                       int t, int gs, float4& xr) {
  const int row = t >> 3;
  const int kq  = t & 7;
  xr = *(const float4*)(x + (size_t)(m0 + row) * HID + gs * 32 + kq * 4);
}

__device__ __forceinline__ void stage_x(const float4& xr,
                                        _Float16* __restrict__ buf, int t) {
  const int row = t >> 3;
  const int kq  = t & 7;
  const float a[4] = {xr.x, xr.y, xr.z, xr.w};
  f16x4 h, l;
#pragma unroll
  for (int i = 0; i < 4; ++i) {
    const _Float16 hi = (_Float16)a[i];
    h[i] = hi;
    l[i] = (_Float16)(a[i] - (float)hi);
  }
  const int off = row * LROW + kq * 4;
  *(f16x4*)&buf[off]          = h;
  *(f16x4*)&buf[LPLANE + off] = l;
}

__device__ __forceinline__ void mfma_step(const _Float16* __restrict__ buf,
                                          const BF& f, int lane,
                                          f32x4 (&acc)[2][2]) {
#pragma unroll
  for (int mi = 0; mi < 2; ++mi) {
    const int off = (mi * 16 + (lane & 15)) * LROW + (lane >> 4) * 8;
    const f16x8 ah = *(const f16x8*)&buf[off];
    const f16x8 al = *(const f16x8*)&buf[LPLANE + off];
#pragma unroll
    for (int g = 0; g < 2; ++g) {
      acc[mi][g] = __builtin_amdgcn_mfma_f32_16x16x32_f16(ah, f.h[g], acc[mi][g], 0, 0, 0);
      acc[mi][g] = __builtin_amdgcn_mfma_f32_16x16x32_f16(al, f.h[g], acc[mi][g], 0, 0, 0);
      acc[mi][g] = __builtin_amdgcn_mfma_f32_16x16x32_f16(ah, f.l[g], acc[mi][g], 0, 0, 0);
    }
  }
}

__global__ __launch_bounds__(256, 4) void logits_mfma(const float* __restrict__ x,
                                                      const _Float16* __restrict__ wc,
                                                      float* __restrict__ part) {
  __shared__ _Float16 xsh[2 * 2 * LPLANE];   // 10240 B

  const int bid  = blockIdx.x;
  const int s    = bid & 3;      // K-chunk; fixed per XCD (bid%8 fixes bid&3)
  const int tile = bid >> 2;     // 0..255
  const int m0   = tile * TM;

  const int t    = threadIdx.x;
  const int lane = t & 63;
  const int wn   = t >> 6;       // expert quarter (32 experts)

  const int kbase = NKS / SPLITK, krem = NKS % SPLITK;
  const int cnt   = kbase + (s < krem ? 1 : 0);
  const int st0   = s * kbase + (s < krem ? s : krem);

  _Float16* buf0 = xsh;
  _Float16* buf1 = xsh + 2 * LPLANE;

  f32x4 acc[2][2] = {};
  float4 xrA, xrB;
  BF bA, bB;

  // prologue: step 0 staged into buf0; x(step1) in flight; B(0) in regs
  load_x(x, m0, t, st0, xrA);
  load_b(wc, wn, lane, st0, bA);
  stage_x(xrA, buf0, t);
  if (cnt > 1) load_x(x, m0, t, st0 + 1, xrB);
  __syncthreads();

  int st = 0;
  for (;;) {
    // even slot: compute buf0/bA; stage st+1 -> buf1
    if (st + 1 < cnt) load_b(wc, wn, lane, st0 + st + 1, bB);
    if (st + 2 < cnt) load_x(x, m0, t, st0 + st + 2, xrA);
    mfma_step(buf0, bA, lane, acc);
    if (st + 1 < cnt) stage_x(xrB, buf1, t);
    __syncthreads();
    if (st + 1 >= cnt) break;

    // odd slot: compute buf1/bB; stage st+2 -> buf0
    if (st + 2 < cnt) load_b(wc, wn, lane, st0 + st + 2, bA);
    if (st + 3 < cnt) load_x(x, m0, t, st0 + st + 3, xrB);
    mfma_step(buf1, bB, lane, acc);
    if (st + 2 < cnt) stage_x(xrA, buf0, t);
    __syncthreads();
    st += 2;
    if (st >= cnt) break;
  }

  // epilogue: C/D layout col=lane&15 (expert), row=(lane>>4)*4+reg (token)
  float* pl = part + (size_t)s * T_TOK * NE;
  const int e0 = wn * 32 + (lane & 15);
  const int r0 = m0 + (lane >> 4) * 4;
#pragma unroll
  for (int mi = 0; mi < 2; ++mi)
#pragma unroll
    for (int g = 0; g < 2; ++g) {
      float* pp = pl + (size_t)(r0 + mi * 16) * NE + e0 + g * 16;
#pragma unroll
      for (int r = 0; r < 4; ++r) pp[(size_t)r * NE] = acc[mi][g][r] * 0.03125f;
    }
}

// ---------------------------------------------------------------------------
// Kernel 2: reduce split-K partials in fixed order + bias (float2/lane),
// per-token top-4 (desc, lower-index tie-break = jax.lax.top_k), softmax,
// plus per-block LDS histogram -> tileHist (NO global atomics, R5 lesson).
// 128 blocks x 4 waves; each wave 16 tokens.
// Out: [0,T*4) scores | [T*4,2*T*4) indices-as-float | [2*T*4,+128) counts
// ---------------------------------------------------------------------------
__global__ __launch_bounds__(256) void topk_hist(const float* __restrict__ part,
                                                 const float* __restrict__ bias,
                                                 float* __restrict__ out,
                                                 float* __restrict__ tileHist) {
  __shared__ int hist[NE];

  const int lane = threadIdx.x & 63;
  const int wave = threadIdx.x >> 6;
  const int blk  = blockIdx.x;          // 64 tokens per block

  for (int e = threadIdx.x; e < NE; e += 256) hist[e] = 0;
  __syncthreads();

  const float2 b2 = ((const float2*)bias)[lane];

  for (int i = 0; i < 16; ++i) {
    const int tok = blk * 64 + wave * 16 + i;

    float v0 = 0.f, v1 = 0.f;
#pragma unroll
    for (int s = 0; s < SPLITK; ++s) {   // fixed order -> deterministic
      const float2 p = ((const float2*)(part + ((size_t)s * T_TOK + tok) * NE))[lane];
      v0 += p.x;
      v1 += p.y;
    }
    v0 += b2.x;
    v1 += b2.y;
    const int i0 = 2 * lane, i1 = 2 * lane + 1;

    float topv[TOPK];
    int   topi[TOPK];
#pragma unroll
    for (int r = 0; r < TOPK; ++r) {
      float bv; int bi;
      if (v0 >= v1) { bv = v0; bi = i0; }   // i0 < i1 implements the tie-break
      else          { bv = v1; bi = i1; }
#pragma unroll
      for (int off = 32; off > 0; off >>= 1) {
        const float ov = __shfl_xor(bv, off);
        const int   oi = __shfl_xor(bi, off);
        if (ov > bv || (ov == bv && oi < bi)) { bv = ov; bi = oi; }
      }
      topv[r] = bv; topi[r] = bi;
      if (bi == i0) v0 = -INFINITY;
      if (bi == i1) v1 = -INFINITY;
    }

    const float m = topv[0];
    float sum = 0.f;
#pragma unroll
    for (int r = 0; r < TOPK; ++r) sum += expf(topv[r] - m);

    if (lane < TOPK) {
      out[(size_t)tok * TOPK + lane] = expf(topv[lane] - m) / sum;
      out[(size_t)T_TOK * TOPK + (size_t)tok * TOPK + lane] = (float)topi[lane];
      atomicAdd(&hist[topi[lane]], 1);   // LDS atomic — cheap, order-free
    }
  }
  __syncthreads();
  for (int e = threadIdx.x; e < NE; e += 256)
    tileHist[(size_t)blk * NE + e] = (float)hist[e];
}

// ---------------------------------------------------------------------------
// Kernel 3: fold 128 per-block histograms (64 KB) into counts. One block.
// ---------------------------------------------------------------------------
__global__ __launch_bounds__(128) void count_reduce(const float* __restrict__ tileHist,
                                                    float* __restrict__ counts) {
  const int e = threadIdx.x;
  float c = 0.f;
  for (int b = 0; b < 128; ++b) c += tileHist[(size_t)b * NE + e];
  counts[e] = c;
}

extern "C" void kernel_launch(void* const* d_in, const int* in_sizes, int n_in,
                              void* d_out, int out_size, void* d_ws, size_t ws_size,
                              hipStream_t stream) {
  const float* x    = (const float*)d_in[0];
  const float* w    = (const float*)d_in[1];
  const float* bias = (const float*)d_in[2];
  float* out = (float*)d_out;

  char* ws = (char*)d_ws;
  float*    part     = (float*)ws;                                   // 16 MB
  size_t    off      = (size_t)SPLITK * T_TOK * NE * sizeof(float);
  _Float16* wc       = (_Float16*)(ws + off);                        // 1.44 MB
  off += (size_t)NE * HID * 2 * sizeof(_Float16);
  float*    tileHist = (float*)(ws + off);                           // 64 KB

  convert_w<<<(NE * (HID / 8) + 255) / 256, 256, 0, stream>>>(w, wc);
  logits_mfma<<<NTILE * SPLITK, 256, 0, stream>>>(x, wc, part);
  topk_hist<<<128, 256, 0, stream>>>(part, bias, out, tileHist);
  count_reduce<<<1, 128, 0, stream>>>(tileHist, out + 2 * (size_t)T_TOK * TOPK);
}

// Round 14
// 80.492 us; speedup vs baseline: 1.9618x; 1.0253x over previous
//
#include <hip/hip_runtime.h>
#include <math.h>

#define T_TOK 8192
#define HID   2880
#define NE    128
#define TOPK  4
#define NKS   (HID / 32)     // 90 K-steps of 32
#define TM    64             // tokens per tile (R8 best-known)
#define SPLITK 4
#define LROW  40             // LDS row stride in halves (80 B)
#define LPLANE (TM * LROW)   // one h- or l-plane, in halves (2560)

typedef _Float16 f16x8 __attribute__((ext_vector_type(8)));
typedef _Float16 f16x4 __attribute__((ext_vector_type(4)));
typedef float    f32x4 __attribute__((ext_vector_type(4)));

// ---------------------------------------------------------------------------
// Kernel 0: W (fp32) -> fragment-linear fp16 hi/lo planes, scaled x32 (keeps
// lo out of denormals; 2^-5 folded into the epilogue). Fragment (32-k step
// gs, expert-group j, plane p) at ((gs*8+j)*2+p)*512 halves; lane
// l=(oct<<4)|(n&15) holds 8 k-consecutive halves = mfma_16x16x32 B chunk.
// ---------------------------------------------------------------------------
__global__ __launch_bounds__(256) void convert_w(const float* __restrict__ w,
                                                 _Float16* __restrict__ wc) {
  const int c = blockIdx.x * 256 + threadIdx.x;   // one 8-k chunk of one expert
  if (c >= NE * (HID / 8)) return;
  const int n  = c / (HID / 8);
  const int k8 = c % (HID / 8);
  const float4 v0 = *(const float4*)(w + (size_t)n * HID + k8 * 8);
  const float4 v1 = *(const float4*)(w + (size_t)n * HID + k8 * 8 + 4);
  const float f[8] = {v0.x, v0.y, v0.z, v0.w, v1.x, v1.y, v1.z, v1.w};
  f16x8 h, l;
#pragma unroll
  for (int i = 0; i < 8; ++i) {
    const float s = f[i] * 32.0f;
    const _Float16 hi = (_Float16)s;
    h[i] = hi;
    l[i] = (_Float16)(s - (float)hi);
  }
  const int gs   = k8 >> 2;
  const int oct  = k8 & 3;
  const int j    = n >> 4;
  const int lane = (oct << 4) | (n & 15);
  _Float16* base = wc + ((size_t)(gs * 8 + j) * 2) * 512 + lane * 8;
  *(f16x8*)(base)       = h;
  *(f16x8*)(base + 512) = l;
}

// ---------------------------------------------------------------------------
// Kernel 1: R8 best-known gemm, verbatim. fp16x2 MFMA emulation of fp32:
// acc += xh*wh + xl*wh + xh*wl, *2^-5. Tile 64 tok x 128 exp, 4 waves
// (32-expert quarter each: mi=4 x nj=2, 24 MFMA/32k-step). split-K=4,
// grid 512 (2 blocks/CU). Double-buffered LDS; x 2 steps ahead, B 1 ahead.
// s=bid&3 swizzle: XCD (bid%8) streams ONE 0.36 MB wc K-chunk.
// Tested & rejected: TM=32/occupancy x2 (R13, +22us), 4-deep prefetch (R11,
// neutral), full-K fusion (R7, +30us), cross-block coherence (R5/R12).
// ---------------------------------------------------------------------------
struct BF { f16x8 h[2], l[2]; };

__device__ __forceinline__ void load_b(const _Float16* __restrict__ wc, int wn,
                                       int lane, int gs, BF& f) {
#pragma unroll
  for (int g = 0; g < 2; ++g) {
    const _Float16* bp = wc + ((size_t)(gs * 8 + wn * 2 + g) * 2) * 512 + lane * 8;
    f.h[g] = *(const f16x8*)bp;
    f.l[g] = *(const f16x8*)(bp + 512);
  }
}

__device__ __forceinline__ void load_x(const float* __restrict__ x, int m0,
                                       int t, int gs, float4 (&xr)[2]) {
#pragma unroll
  for (int j = 0; j < 2; ++j) {
    const int c   = j * 256 + t;
    const int row = c >> 3;
    const int kq  = c & 7;
    xr[j] = *(const float4*)(x + (size_t)(m0 + row) * HID + gs * 32 + kq * 4);
  }
}

__device__ __forceinline__ void stage_x(const float4 (&xr)[2],
                                        _Float16* __restrict__ buf, int t) {
#pragma unroll
  for (int j = 0; j < 2; ++j) {
    const int c   = j * 256 + t;
    const int row = c >> 3;
    const int kq  = c & 7;
    const float a[4] = {xr[j].x, xr[j].y, xr[j].z, xr[j].w};
    f16x4 h, l;
#pragma unroll
    for (int i = 0; i < 4; ++i) {
      const _Float16 hi = (_Float16)a[i];
      h[i] = hi;
      l[i] = (_Float16)(a[i] - (float)hi);
    }
    const int off = row * LROW + kq * 4;
    *(f16x4*)&buf[off]          = h;
    *(f16x4*)&buf[LPLANE + off] = l;
  }
}

__device__ __forceinline__ void mfma_step(const _Float16* __restrict__ buf,
                                          const BF& f, int lane,
                                          f32x4 (&acc)[4][2]) {
#pragma unroll
  for (int mi = 0; mi < 4; ++mi) {
    const int off = (mi * 16 + (lane & 15)) * LROW + (lane >> 4) * 8;
    const f16x8 ah = *(const f16x8*)&buf[off];
    const f16x8 al = *(const f16x8*)&buf[LPLANE + off];
#pragma unroll
    for (int g = 0; g < 2; ++g) {
      acc[mi][g] = __builtin_amdgcn_mfma_f32_16x16x32_f16(ah, f.h[g], acc[mi][g], 0, 0, 0);
      acc[mi][g] = __builtin_amdgcn_mfma_f32_16x16x32_f16(al, f.h[g], acc[mi][g], 0, 0, 0);
      acc[mi][g] = __builtin_amdgcn_mfma_f32_16x16x32_f16(ah, f.l[g], acc[mi][g], 0, 0, 0);
    }
  }
}

__global__ __launch_bounds__(256, 2) void logits_mfma(const float* __restrict__ x,
                                                      const _Float16* __restrict__ wc,
                                                      float* __restrict__ part) {
  __shared__ _Float16 xsh[2 * 2 * LPLANE];   // 20480 B

  const int bid = blockIdx.x;
  // R8 swizzle: s fixed per XCD (bid%8 fixes bid&3), tiles spread
  const int s    = bid & 3;
  const int tile = ((bid >> 3) << 1) | ((bid & 7) >> 2);
  const int m0   = tile * TM;

  const int t    = threadIdx.x;
  const int lane = t & 63;
  const int wn   = t >> 6;       // expert quarter (32 experts)

  const int kbase = NKS / SPLITK, krem = NKS % SPLITK;
  const int cnt   = kbase + (s < krem ? 1 : 0);
  const int st0   = s * kbase + (s < krem ? s : krem);

  _Float16* buf0 = xsh;
  _Float16* buf1 = xsh + 2 * LPLANE;

  f32x4 acc[4][2] = {};
  float4 xrA[2], xrB[2];
  BF bA, bB;

  // prologue: step 0 staged into buf0; x(step1) in flight; B(0) in regs
  load_x(x, m0, t, st0, xrA);
  load_b(wc, wn, lane, st0, bA);
  stage_x(xrA, buf0, t);
  if (cnt > 1) load_x(x, m0, t, st0 + 1, xrB);
  __syncthreads();

  int st = 0;
  for (;;) {
    // even slot: compute buf0/bA; stage st+1 -> buf1
    if (st + 1 < cnt) load_b(wc, wn, lane, st0 + st + 1, bB);
    if (st + 2 < cnt) load_x(x, m0, t, st0 + st + 2, xrA);
    mfma_step(buf0, bA, lane, acc);
    if (st + 1 < cnt) stage_x(xrB, buf1, t);
    __syncthreads();
    if (st + 1 >= cnt) break;

    // odd slot: compute buf1/bB; stage st+2 -> buf0
    if (st + 2 < cnt) load_b(wc, wn, lane, st0 + st + 2, bA);
    if (st + 3 < cnt) load_x(x, m0, t, st0 + st + 3, xrB);
    mfma_step(buf1, bB, lane, acc);
    if (st + 2 < cnt) stage_x(xrA, buf0, t);
    __syncthreads();
    st += 2;
    if (st >= cnt) break;
  }

  // epilogue: C/D layout col=lane&15 (expert), row=(lane>>4)*4+reg (token)
  float* pl = part + (size_t)s * T_TOK * NE;
  const int e0 = wn * 32 + (lane & 15);
  const int r0 = m0 + (lane >> 4) * 4;
#pragma unroll
  for (int mi = 0; mi < 4; ++mi)
#pragma unroll
    for (int g = 0; g < 2; ++g) {
      float* pp = pl + (size_t)(r0 + mi * 16) * NE + e0 + g * 16;
#pragma unroll
      for (int r = 0; r < 4; ++r) pp[(size_t)r * NE] = acc[mi][g][r] * 0.03125f;
    }
}

// ---------------------------------------------------------------------------
// Kernel 2: reduce split-K partials in fixed order + bias (float2/lane),
// per-token top-4 (desc, lower-index tie-break = jax.lax.top_k), softmax,
// plus per-block LDS histogram -> tileHist (NO global atomics, R5 lesson;
// replaces the 16 MB-rescanning count_kernel). 128 blocks x 4 waves.
// Out: [0,T*4) scores | [T*4,2*T*4) indices-as-float | [2*T*4,+128) counts
// ---------------------------------------------------------------------------
__global__ __launch_bounds__(256) void topk_hist(const float* __restrict__ part,
                                                 const float* __restrict__ bias,
                                                 float* __restrict__ out,
                                                 float* __restrict__ tileHist) {
  __shared__ int hist[NE];

  const int lane = threadIdx.x & 63;
  const int wave = threadIdx.x >> 6;
  const int blk  = blockIdx.x;          // 64 tokens per block

  for (int e = threadIdx.x; e < NE; e += 256) hist[e] = 0;
  __syncthreads();

  const float2 b2 = ((const float2*)bias)[lane];

  for (int i = 0; i < 16; ++i) {
    const int tok = blk * 64 + wave * 16 + i;

    float v0 = 0.f, v1 = 0.f;
#pragma unroll
    for (int s = 0; s < SPLITK; ++s) {   // fixed order -> deterministic
      const float2 p = ((const float2*)(part + ((size_t)s * T_TOK + tok) * NE))[lane];
      v0 += p.x;
      v1 += p.y;
    }
    v0 += b2.x;
    v1 += b2.y;
    const int i0 = 2 * lane, i1 = 2 * lane + 1;

    float topv[TOPK];
    int   topi[TOPK];
#pragma unroll
    for (int r = 0; r < TOPK; ++r) {
      float bv; int bi;
      if (v0 >= v1) { bv = v0; bi = i0; }   // i0 < i1 implements the tie-break
      else          { bv = v1; bi = i1; }
#pragma unroll
      for (int off = 32; off > 0; off >>= 1) {
        const float ov = __shfl_xor(bv, off);
        const int   oi = __shfl_xor(bi, off);
        if (ov > bv || (ov == bv && oi < bi)) { bv = ov; bi = oi; }
      }
      topv[r] = bv; topi[r] = bi;
      if (bi == i0) v0 = -INFINITY;
      if (bi == i1) v1 = -INFINITY;
    }

    const float m = topv[0];
    float sum = 0.f;
#pragma unroll
    for (int r = 0; r < TOPK; ++r) sum += expf(topv[r] - m);

    if (lane < TOPK) {
      out[(size_t)tok * TOPK + lane] = expf(topv[lane] - m) / sum;
      out[(size_t)T_TOK * TOPK + (size_t)tok * TOPK + lane] = (float)topi[lane];
      atomicAdd(&hist[topi[lane]], 1);   // LDS atomic — cheap, order-free
    }
  }
  __syncthreads();
  for (int e = threadIdx.x; e < NE; e += 256)
    tileHist[(size_t)blk * NE + e] = (float)hist[e];
}

// ---------------------------------------------------------------------------
// Kernel 3: fold 128 per-block histograms (64 KB) into counts. One block.
// ---------------------------------------------------------------------------
__global__ __launch_bounds__(128) void count_reduce(const float* __restrict__ tileHist,
                                                    float* __restrict__ counts) {
  const int e = threadIdx.x;
  float c = 0.f;
  for (int b = 0; b < 128; ++b) c += tileHist[(size_t)b * NE + e];
  counts[e] = c;
}

extern "C" void kernel_launch(void* const* d_in, const int* in_sizes, int n_in,
                              void* d_out, int out_size, void* d_ws, size_t ws_size,
                              hipStream_t stream) {
  const float* x    = (const float*)d_in[0];
  const float* w    = (const float*)d_in[1];
  const float* bias = (const float*)d_in[2];
  float* out = (float*)d_out;

  char* ws = (char*)d_ws;
  float*    part     = (float*)ws;                                   // 16 MB
  size_t    off      = (size_t)SPLITK * T_TOK * NE * sizeof(float);
  _Float16* wc       = (_Float16*)(ws + off);                        // 1.44 MB
  off += (size_t)NE * HID * 2 * sizeof(_Float16);
  float*    tileHist = (float*)(ws + off);                           // 64 KB

  convert_w<<<(NE * (HID / 8) + 255) / 256, 256, 0, stream>>>(w, wc);
  logits_mfma<<<(T_TOK / TM) * SPLITK, 256, 0, stream>>>(x, wc, part);
  topk_hist<<<128, 256, 0, stream>>>(part, bias, out, tileHist);
  count_reduce<<<1, 128, 0, stream>>>(tileHist, out + 2 * (size_t)T_TOK * TOPK);
}

// Round 15
// 60.697 us; speedup vs baseline: 2.6016x; 1.3261x over previous
//
#include <hip/hip_runtime.h>
#include <math.h>

#define T_TOK 8192
#define HID   2880
#define NE    128
#define TOPK  4
#define NKS   (HID / 32)     // 90 K-steps of 32
#define TM    64             // tokens per tile
#define SPLITK 4
#define LROW  40             // LDS row stride in halves (80 B)
#define LPLANE (TM * LROW)   // one h- or l-plane, in halves (2560)

typedef _Float16 f16x8 __attribute__((ext_vector_type(8)));
typedef _Float16 f16x4 __attribute__((ext_vector_type(4)));
typedef float    f32x4 __attribute__((ext_vector_type(4)));

// ---------------------------------------------------------------------------
// Kernel 0: W (fp32) -> fragment-linear fp16 hi/lo planes, scaled x32 (keeps
// lo out of denormals; 2^-5 folded into the epilogue). Fragment (32-k step
// gs, expert-group j, plane p) at ((gs*8+j)*2+p)*512 halves; lane
// l=(oct<<4)|(n&15) holds 8 k-consecutive halves = mfma_16x16x32 B chunk.
// ---------------------------------------------------------------------------
__global__ __launch_bounds__(256) void convert_w(const float* __restrict__ w,
                                                 _Float16* __restrict__ wc) {
  const int c = blockIdx.x * 256 + threadIdx.x;   // one 8-k chunk of one expert
  if (c >= NE * (HID / 8)) return;
  const int n  = c / (HID / 8);
  const int k8 = c % (HID / 8);
  const float4 v0 = *(const float4*)(w + (size_t)n * HID + k8 * 8);
  const float4 v1 = *(const float4*)(w + (size_t)n * HID + k8 * 8 + 4);
  const float f[8] = {v0.x, v0.y, v0.z, v0.w, v1.x, v1.y, v1.z, v1.w};
  f16x8 h, l;
#pragma unroll
  for (int i = 0; i < 8; ++i) {
    const float s = f[i] * 32.0f;
    const _Float16 hi = (_Float16)s;
    h[i] = hi;
    l[i] = (_Float16)(s - (float)hi);
  }
  const int gs   = k8 >> 2;
  const int oct  = k8 & 3;
  const int j    = n >> 4;
  const int lane = (oct << 4) | (n & 15);
  _Float16* base = wc + ((size_t)(gs * 8 + j) * 2) * 512 + lane * 8;
  *(f16x8*)(base)       = h;
  *(f16x8*)(base + 512) = l;
}

// ---------------------------------------------------------------------------
// Kernel 1: partial logits via fp16x2 MFMA emulation of fp32:
// acc += xh*wh + xl*wh + xh*wl, *2^-5 at the end. Tile 64 tok x 128 exp,
// 4 waves (one 32-expert quarter each: mi=4 x nj=2, 24 MFMA/32k-step).
// split-K=4 -> grid 512 (2 blocks/CU). Double-buffered LDS; x prefetched
// 2 steps ahead, B 1 step ahead (L2-hot). s=bid&3 swizzle: each XCD
// (bid%8 fixes bid&3) streams ONE 0.36 MB wc K-chunk.
// EMPIRICAL BEST (60.7 us total). Tested & rejected: TM=32/occupancy x2
// (R13 +22us), 4-deep prefetch (R11 neutral), full-K fusion (R7 +30us),
// cross-block coherence (R5/R12 catastrophic), ntload+affinity (R10 +12us),
// narrow-grid tail fusion (R14 +20us).
// ---------------------------------------------------------------------------
struct BF { f16x8 h[2], l[2]; };

__device__ __forceinline__ void load_b(const _Float16* __restrict__ wc, int wn,
                                       int lane, int gs, BF& f) {
#pragma unroll
  for (int g = 0; g < 2; ++g) {
    const _Float16* bp = wc + ((size_t)(gs * 8 + wn * 2 + g) * 2) * 512 + lane * 8;
    f.h[g] = *(const f16x8*)bp;
    f.l[g] = *(const f16x8*)(bp + 512);
  }
}

__device__ __forceinline__ void load_x(const float* __restrict__ x, int m0,
                                       int t, int gs, float4 (&xr)[2]) {
#pragma unroll
  for (int j = 0; j < 2; ++j) {
    const int c   = j * 256 + t;
    const int row = c >> 3;
    const int kq  = c & 7;
    xr[j] = *(const float4*)(x + (size_t)(m0 + row) * HID + gs * 32 + kq * 4);
  }
}

__device__ __forceinline__ void stage_x(const float4 (&xr)[2],
                                        _Float16* __restrict__ buf, int t) {
#pragma unroll
  for (int j = 0; j < 2; ++j) {
    const int c   = j * 256 + t;
    const int row = c >> 3;
    const int kq  = c & 7;
    const float a[4] = {xr[j].x, xr[j].y, xr[j].z, xr[j].w};
    f16x4 h, l;
#pragma unroll
    for (int i = 0; i < 4; ++i) {
      const _Float16 hi = (_Float16)a[i];
      h[i] = hi;
      l[i] = (_Float16)(a[i] - (float)hi);
    }
    const int off = row * LROW + kq * 4;
    *(f16x4*)&buf[off]          = h;
    *(f16x4*)&buf[LPLANE + off] = l;
  }
}

__device__ __forceinline__ void mfma_step(const _Float16* __restrict__ buf,
                                          const BF& f, int lane,
                                          f32x4 (&acc)[4][2]) {
#pragma unroll
  for (int mi = 0; mi < 4; ++mi) {
    const int off = (mi * 16 + (lane & 15)) * LROW + (lane >> 4) * 8;
    const f16x8 ah = *(const f16x8*)&buf[off];
    const f16x8 al = *(const f16x8*)&buf[LPLANE + off];
#pragma unroll
    for (int g = 0; g < 2; ++g) {
      acc[mi][g] = __builtin_amdgcn_mfma_f32_16x16x32_f16(ah, f.h[g], acc[mi][g], 0, 0, 0);
      acc[mi][g] = __builtin_amdgcn_mfma_f32_16x16x32_f16(al, f.h[g], acc[mi][g], 0, 0, 0);
      acc[mi][g] = __builtin_amdgcn_mfma_f32_16x16x32_f16(ah, f.l[g], acc[mi][g], 0, 0, 0);
    }
  }
}

__global__ __launch_bounds__(256, 2) void logits_mfma(const float* __restrict__ x,
                                                      const _Float16* __restrict__ wc,
                                                      float* __restrict__ part) {
  __shared__ _Float16 xsh[2 * 2 * LPLANE];   // 20480 B

  const int bid = blockIdx.x;
  // swizzle: s fixed per XCD (bid%8 fixes bid&3), tiles spread
  const int s    = bid & 3;
  const int tile = ((bid >> 3) << 1) | ((bid & 7) >> 2);
  const int m0   = tile * TM;

  const int t    = threadIdx.x;
  const int lane = t & 63;
  const int wn   = t >> 6;       // expert quarter (32 experts)

  const int kbase = NKS / SPLITK, krem = NKS % SPLITK;
  const int cnt   = kbase + (s < krem ? 1 : 0);
  const int st0   = s * kbase + (s < krem ? s : krem);

  _Float16* buf0 = xsh;
  _Float16* buf1 = xsh + 2 * LPLANE;

  f32x4 acc[4][2] = {};
  float4 xrA[2], xrB[2];
  BF bA, bB;

  // prologue: step 0 staged into buf0; x(step1) in flight; B(0) in regs
  load_x(x, m0, t, st0, xrA);
  load_b(wc, wn, lane, st0, bA);
  stage_x(xrA, buf0, t);
  if (cnt > 1) load_x(x, m0, t, st0 + 1, xrB);
  __syncthreads();

  int st = 0;
  for (;;) {
    // even slot: compute buf0/bA; stage st+1 -> buf1
    if (st + 1 < cnt) load_b(wc, wn, lane, st0 + st + 1, bB);
    if (st + 2 < cnt) load_x(x, m0, t, st0 + st + 2, xrA);
    mfma_step(buf0, bA, lane, acc);
    if (st + 1 < cnt) stage_x(xrB, buf1, t);
    __syncthreads();
    if (st + 1 >= cnt) break;

    // odd slot: compute buf1/bB; stage st+2 -> buf0
    if (st + 2 < cnt) load_b(wc, wn, lane, st0 + st + 2, bA);
    if (st + 3 < cnt) load_x(x, m0, t, st0 + st + 3, xrB);
    mfma_step(buf1, bB, lane, acc);
    if (st + 2 < cnt) stage_x(xrA, buf0, t);
    __syncthreads();
    st += 2;
    if (st >= cnt) break;
  }

  // epilogue: C/D layout col=lane&15 (expert), row=(lane>>4)*4+reg (token)
  float* pl = part + (size_t)s * T_TOK * NE;
  const int e0 = wn * 32 + (lane & 15);
  const int r0 = m0 + (lane >> 4) * 4;
#pragma unroll
  for (int mi = 0; mi < 4; ++mi)
#pragma unroll
    for (int g = 0; g < 2; ++g) {
      float* pp = pl + (size_t)(r0 + mi * 16) * NE + e0 + g * 16;
#pragma unroll
      for (int r = 0; r < 4; ++r) pp[(size_t)r * NE] = acc[mi][g][r] * 0.03125f;
    }
}

// ---------------------------------------------------------------------------
// Kernel 2: reduce split-K partials in fixed order + bias (float2/lane),
// per-token top-4 (desc, lower-index tie-break = jax.lax.top_k), softmax.
// NO atomics (R5 lesson). One wave per token, 2048 blocks — grid WIDTH is
// what hides the latency-bound plane reads (R14 lesson: 128 blocks = +20us).
// Out: [0,T*4) scores | [T*4,2*T*4) indices-as-float | [2*T*4,+128) counts
// ---------------------------------------------------------------------------
__global__ __launch_bounds__(256) void topk_kernel(const float* __restrict__ part,
                                                   const float* __restrict__ bias,
                                                   float* __restrict__ out) {
  const int lane = threadIdx.x & 63;
  const int wave = threadIdx.x >> 6;
  const int tok  = blockIdx.x * 4 + wave;

  float v0 = 0.f, v1 = 0.f;
#pragma unroll
  for (int s = 0; s < SPLITK; ++s) {   // fixed order -> deterministic
    const float2 p = ((const float2*)(part + ((size_t)s * T_TOK + tok) * NE))[lane];
    v0 += p.x;
    v1 += p.y;
  }
  const float2 b2 = ((const float2*)bias)[lane];
  v0 += b2.x;
  v1 += b2.y;
  const int i0 = 2 * lane, i1 = 2 * lane + 1;

  float topv[TOPK];
  int   topi[TOPK];

#pragma unroll
  for (int r = 0; r < TOPK; ++r) {
    float bv; int bi;
    if (v0 >= v1) { bv = v0; bi = i0; }   // i0 < i1 implements lower-index tie-break
    else          { bv = v1; bi = i1; }
#pragma unroll
    for (int off = 32; off > 0; off >>= 1) {
      const float ov = __shfl_xor(bv, off);
      const int   oi = __shfl_xor(bi, off);
      if (ov > bv || (ov == bv && oi < bi)) { bv = ov; bi = oi; }
    }
    topv[r] = bv; topi[r] = bi;
    if (bi == i0) v0 = -INFINITY;
    if (bi == i1) v1 = -INFINITY;
  }

  const float m = topv[0];
  float sum = 0.f;
#pragma unroll
  for (int r = 0; r < TOPK; ++r) sum += expf(topv[r] - m);

  if (lane < TOPK) {
    out[(size_t)tok * TOPK + lane] = expf(topv[lane] - m) / sum;
    out[(size_t)T_TOK * TOPK + (size_t)tok * TOPK + lane] = (float)topi[lane];
  }
}

// ---------------------------------------------------------------------------
// Kernel 3: expert histogram, atomic-free & deterministic. One block per
// expert scans the 32768 index floats (128 KB, L2-resident). Direct write.
// ---------------------------------------------------------------------------
__global__ __launch_bounds__(256) void count_kernel(const float* __restrict__ idxf,
                                                    float* __restrict__ counts) {
  const int e = blockIdx.x;
  const int t = threadIdx.x;
  const float ef = (float)e;
  int c = 0;
  for (int i = t; i < T_TOK * TOPK; i += 256)
    c += (idxf[i] == ef) ? 1 : 0;
#pragma unroll
  for (int off = 32; off > 0; off >>= 1) c += __shfl_xor(c, off);
  __shared__ int shred[4];
  if ((t & 63) == 0) shred[t >> 6] = c;
  __syncthreads();
  if (t == 0) counts[e] = (float)(shred[0] + shred[1] + shred[2] + shred[3]);
}

extern "C" void kernel_launch(void* const* d_in, const int* in_sizes, int n_in,
                              void* d_out, int out_size, void* d_ws, size_t ws_size,
                              hipStream_t stream) {
  const float* x    = (const float*)d_in[0];
  const float* w    = (const float*)d_in[1];
  const float* bias = (const float*)d_in[2];
  float* out  = (float*)d_out;
  float* part = (float*)d_ws;                                     // 4 planes, 16 MB
  _Float16* wc = (_Float16*)((char*)d_ws +
                             (size_t)SPLITK * T_TOK * NE * sizeof(float));

  convert_w<<<(NE * (HID / 8) + 255) / 256, 256, 0, stream>>>(w, wc);
  logits_mfma<<<(T_TOK / TM) * SPLITK, 256, 0, stream>>>(x, wc, part);
  topk_kernel<<<T_TOK / 4, 256, 0, stream>>>(part, bias, out);
  count_kernel<<<NE, 256, 0, stream>>>(out + (size_t)T_TOK * TOPK,
                                       out + 2 * (size_t)T_TOK * TOPK);
}